// Round 12
// baseline (441.882 us; speedup 1.0000x reference)
//
#include <hip/hip_runtime.h>
#include <hip/hip_bf16.h>
#include <cstdint>

// ---------------------------------------------------------------------------
// Transformer block forward (B=4,T=2048,H=16,D=64,C=1024,FF=4096), bf16 MFMA.
// Round 19: distance-2 prefetch GEMM for Wout only. Mechanism: Wout's A
// operand (hb, 64MB) misses L2 -> ~900cy loads > ~600cy compute span, so the
// m97 structure exposes HBM latency every K-step (1620 cy/step measured vs
// FC's 860 with L2-resident A). Fix: A triple-buffered (stage t+2), B
// double-buffered (stage t+1), counted vmcnt(4) at each step (T4: never
// drain to 0 — round-3's dbuf failed precisely because vmcnt(0) re-exposed
// the latency). 80KB LDS -> still 2 blocks/CU. All other kernels byte-
// identical to the locked 433 µs build.
// ---------------------------------------------------------------------------

#define B_ 4
#define T_ 2048
#define H_ 16
#define D_ 64
#define C_ 1024
#define FF_ 4096
#define M_ (B_ * T_)          // 8192 rows
#define QKV_N (3 * C_)        // 3072

typedef __bf16 bf16x8 __attribute__((ext_vector_type(8)));
typedef __bf16 bf16x4 __attribute__((ext_vector_type(4)));
typedef float floatx4 __attribute__((ext_vector_type(4)));

#define MFMA16(a, b, c) __builtin_amdgcn_mfma_f32_16x16x32_bf16(a, b, c, 0, 0, 0)

__device__ __forceinline__ void gload16(const void* g, void* l) {
  __builtin_amdgcn_global_load_lds(
      (const __attribute__((address_space(1))) void*)g,
      (__attribute__((address_space(3))) void*)l, 16, 0, 0);
}

__device__ __forceinline__ void lds_fence() {
  asm volatile("s_waitcnt lgkmcnt(0)" ::: "memory");
}

// raw barrier: does NOT drain vmcnt (unlike __syncthreads)
__device__ __forceinline__ void bar() {
  asm volatile("" ::: "memory");
  __builtin_amdgcn_s_barrier();
  asm volatile("" ::: "memory");
}
__device__ __forceinline__ void waitvm4() {
  asm volatile("s_waitcnt vmcnt(4)" ::: "memory");
}
__device__ __forceinline__ void waitvm0() {
  asm volatile("s_waitcnt vmcnt(0)" ::: "memory");
}

// tanh-approx GELU via exp2: gelu(x) = x - x/(exp2(k1*x + ck*x^3) + 1)
__device__ __forceinline__ float gelu_f(float x) {
  const float k1 = 2.3021178518f;     // 2*log2(e)*0.7978845608
  const float ck = 0.1029410426f;     // k1*0.044715
  const float y = x * __builtin_fmaf(x * x, ck, k1);
  const float t = __builtin_amdgcn_exp2f(y);
  return x - x * __builtin_amdgcn_rcpf(t + 1.0f);
}

// ---------------- head: weight convert+transpose (x4) + LN1 ----------------
__global__ __launch_bounds__(256) void head_kernel(
    const float* __restrict__ wqkv, const float* __restrict__ wo,
    const float* __restrict__ wfc, const float* __restrict__ wout,
    __bf16* __restrict__ dqkv, __bf16* __restrict__ dwo,
    __bf16* __restrict__ dfc, __bf16* __restrict__ dwout,
    const float* __restrict__ x, const float* __restrict__ lnw,
    const float* __restrict__ lnb, __bf16* __restrict__ xn) {
  __shared__ float tile[32][33];
  __shared__ float red[4];
  int bx = blockIdx.x;
  const int tid = threadIdx.x;

  if (bx >= 12288) {
    const int row = bx - 12288;
    const float4 v = ((const float4*)(x + (size_t)row * C_))[tid];
    float s = v.x + v.y + v.z + v.w;
#pragma unroll
    for (int off = 1; off < 64; off <<= 1) s += __shfl_xor(s, off, 64);
    if ((tid & 63) == 0) red[tid >> 6] = s;
    __syncthreads();
    const float mean = (red[0] + red[1] + red[2] + red[3]) * (1.0f / C_);
    __syncthreads();
    const float dx = v.x - mean, dy = v.y - mean, dz = v.z - mean,
                dw = v.w - mean;
    float s2 = dx * dx + dy * dy + dz * dz + dw * dw;
#pragma unroll
    for (int off = 1; off < 64; off <<= 1) s2 += __shfl_xor(s2, off, 64);
    if ((tid & 63) == 0) red[tid >> 6] = s2;
    __syncthreads();
    const float var = (red[0] + red[1] + red[2] + red[3]) * (1.0f / C_);
    const float rstd = rsqrtf(var + 1e-5f);
    const float4 wv = ((const float4*)lnw)[tid];
    const float4 bv = ((const float4*)lnb)[tid];
    bf16x4 o;
    o[0] = (__bf16)(dx * rstd * wv.x + bv.x);
    o[1] = (__bf16)(dy * rstd * wv.y + bv.y);
    o[2] = (__bf16)(dz * rstd * wv.z + bv.z);
    o[3] = (__bf16)(dw * rstd * wv.w + bv.w);
    *(bf16x4*)(xn + (size_t)row * C_ + tid * 4) = o;
    return;
  }

  const float* src;
  __bf16* dst;
  int K, N;
  if (bx < 3072)      { src = wqkv; dst = dqkv; K = 1024; N = 3072; }
  else if (bx < 4096) { bx -= 3072; src = wo;   dst = dwo;   K = 1024; N = 1024; }
  else if (bx < 8192) { bx -= 4096; src = wfc;  dst = dfc;   K = 1024; N = 4096; }
  else                { bx -= 8192; src = wout; dst = dwout; K = 4096; N = 1024; }
  const int tn = N >> 5;
  const int n0 = (bx % tn) * 32, k0 = (bx / tn) * 32;
  const int tx = tid & 31, ty = tid >> 5;  // 32 x 8
#pragma unroll
  for (int i = 0; i < 4; ++i)
    tile[ty + i * 8][tx] = src[(size_t)(k0 + ty + i * 8) * N + n0 + tx];
  __syncthreads();
#pragma unroll
  for (int i = 0; i < 4; ++i)
    dst[(size_t)(n0 + ty + i * 8) * K + k0 + tx] = (__bf16)tile[tx][ty + i * 8];
}

// --------------------------- layernorm (LN2) -------------------------------
__global__ __launch_bounds__(256) void ln_kernel(
    const float* __restrict__ x, const float* __restrict__ w,
    const float* __restrict__ b, __bf16* __restrict__ out) {
  __shared__ float red[4];
  const int row = blockIdx.x, tid = threadIdx.x;
  const float4 v = ((const float4*)(x + (size_t)row * C_))[tid];
  float s = v.x + v.y + v.z + v.w;
#pragma unroll
  for (int off = 1; off < 64; off <<= 1) s += __shfl_xor(s, off, 64);
  if ((tid & 63) == 0) red[tid >> 6] = s;
  __syncthreads();
  const float mean = (red[0] + red[1] + red[2] + red[3]) * (1.0f / C_);
  __syncthreads();
  const float dx = v.x - mean, dy = v.y - mean, dz = v.z - mean, dw = v.w - mean;
  float s2 = dx * dx + dy * dy + dz * dz + dw * dw;
#pragma unroll
  for (int off = 1; off < 64; off <<= 1) s2 += __shfl_xor(s2, off, 64);
  if ((tid & 63) == 0) red[tid >> 6] = s2;
  __syncthreads();
  const float var = (red[0] + red[1] + red[2] + red[3]) * (1.0f / C_);
  const float rstd = rsqrtf(var + 1e-5f);
  const float4 wv = ((const float4*)w)[tid];
  const float4 bv = ((const float4*)b)[tid];
  bf16x4 o;
  o[0] = (__bf16)(dx * rstd * wv.x + bv.x);
  o[1] = (__bf16)(dy * rstd * wv.y + bv.y);
  o[2] = (__bf16)(dz * rstd * wv.z + bv.z);
  o[3] = (__bf16)(dw * rstd * wv.w + bv.w);
  *(bf16x4*)(out + (size_t)row * C_ + tid * 4) = o;
}

// --------------------- swizzle: XCD band + 8x8 L2 groups -------------------
__device__ __forceinline__ void swizzle_mn(int gx, int gy, int* bm, int* bn) {
  const int linear = blockIdx.y * gx + blockIdx.x;
  const int xcd = linear & 7, idx = linear >> 3;
  const int band = gy >> 3;
  const int per_grp = band * 8;
  const int g = idx / per_grp, rem = idx % per_grp;
  *bm = xcd * band + rem % band;
  *bn = g * 8 + rem / band;
}

// ------------------------------- GEMM 128x128 ------------------------------
template <bool GELU, bool RESID, bool OUTBF16>
__global__ __launch_bounds__(256, 2) void gemm_kernel(
    const __bf16* __restrict__ A, const __bf16* __restrict__ BT,
    const float* __restrict__ bias, const float* __restrict__ resid,
    float* __restrict__ outF, __bf16* __restrict__ outB, int M, int N, int K) {
  __shared__ __bf16 As[128 * 64];
  __shared__ __bf16 Bs[128 * 64];
  const int tid = threadIdx.x;
  const int wave = tid >> 6, lane = tid & 63;
  const int lane15 = lane & 15, quad = lane >> 4;
  const int r7 = lane15 & 7;

  int bm, bn;
  swizzle_mn(gridDim.x, gridDim.y, &bm, &bn);
  const int m0 = bm * 128, n0 = bn * 128;
  const int wm = (wave >> 1) * 64, wn = (wave & 1) * 64;

  const int srow = lane >> 3;                 // 0..7 within 8-row chunk
  const int gc8 = (lane & 7) ^ srow;          // xor-swizzled column group

  floatx4 acc[4][4] = {};

  for (int k0 = 0; k0 < K; k0 += 64) {
#pragma unroll
    for (int t = 0; t < 4; ++t) {
      const int row = wave * 32 + t * 8;
      gload16(A + (size_t)(m0 + row + srow) * K + k0 + gc8 * 8, &As[row * 64]);
      gload16(BT + (size_t)(n0 + row + srow) * K + k0 + gc8 * 8, &Bs[row * 64]);
    }
    __syncthreads();
#pragma unroll
    for (int kk8 = 0; kk8 < 8; kk8 += 4) {
      bf16x8 af[4], bfr[4];
#pragma unroll
      for (int i = 0; i < 4; ++i) {
        af[i] = *(const bf16x8*)
            &As[(wm + i * 16 + lane15) * 64 + (((kk8 + quad) ^ r7) << 3)];
        bfr[i] = *(const bf16x8*)
            &Bs[(wn + i * 16 + lane15) * 64 + (((kk8 + quad) ^ r7) << 3)];
      }
#pragma unroll
      for (int i = 0; i < 4; ++i)
#pragma unroll
        for (int j = 0; j < 4; ++j) acc[i][j] = MFMA16(af[i], bfr[j], acc[i][j]);
    }
    __syncthreads();
  }

#pragma unroll
  for (int mi = 0; mi < 4; ++mi) {
    const int row = m0 + wm + mi * 16 + quad * 4;
#pragma unroll
    for (int ni = 0; ni < 4; ++ni) {
      const int col = n0 + wn + ni * 16 + lane15;
      const float bsum = bias[col];
#pragma unroll
      for (int r = 0; r < 4; ++r) {
        const size_t idx2 = (size_t)(row + r) * N + col;
        float v = acc[mi][ni][r] + bsum;
        if (GELU) v = gelu_f(v);
        if (RESID) v += resid[idx2];
        if (OUTBF16) outB[idx2] = (__bf16)v;
        else outF[idx2] = v;
      }
    }
  }
}

// ------------------------------- GEMM 128x64 -------------------------------
template <bool GELU, bool RESID, bool OUTBF16>
__global__ __launch_bounds__(256, 4) void gemm_n64_kernel(
    const __bf16* __restrict__ A, const __bf16* __restrict__ BT,
    const float* __restrict__ bias, const float* __restrict__ resid,
    float* __restrict__ outF, __bf16* __restrict__ outB, int M, int N, int K) {
  __shared__ __bf16 As[128 * 64];
  __shared__ __bf16 Bs[64 * 64];
  const int tid = threadIdx.x;
  const int wave = tid >> 6, lane = tid & 63;
  const int lane15 = lane & 15, quad = lane >> 4;
  const int r7 = lane15 & 7;

  int bm, bn;
  swizzle_mn(gridDim.x, gridDim.y, &bm, &bn);
  const int m0 = bm * 128, n0 = bn * 64;
  const int wm = (wave >> 1) * 64, wn = (wave & 1) * 32;

  const int srow = lane >> 3;
  const int gc8 = (lane & 7) ^ srow;

  floatx4 acc[4][2] = {};

  for (int k0 = 0; k0 < K; k0 += 64) {
#pragma unroll
    for (int t = 0; t < 4; ++t) {
      const int row = wave * 32 + t * 8;
      gload16(A + (size_t)(m0 + row + srow) * K + k0 + gc8 * 8, &As[row * 64]);
    }
#pragma unroll
    for (int t = 0; t < 2; ++t) {
      const int row = wave * 16 + t * 8;
      gload16(BT + (size_t)(n0 + row + srow) * K + k0 + gc8 * 8, &Bs[row * 64]);
    }
    __syncthreads();
#pragma unroll
    for (int kk8 = 0; kk8 < 8; kk8 += 4) {
      bf16x8 af[4], bfr[2];
#pragma unroll
      for (int i = 0; i < 4; ++i)
        af[i] = *(const bf16x8*)
            &As[(wm + i * 16 + lane15) * 64 + (((kk8 + quad) ^ r7) << 3)];
#pragma unroll
      for (int j = 0; j < 2; ++j)
        bfr[j] = *(const bf16x8*)
            &Bs[(wn + j * 16 + lane15) * 64 + (((kk8 + quad) ^ r7) << 3)];
#pragma unroll
      for (int i = 0; i < 4; ++i)
#pragma unroll
        for (int j = 0; j < 2; ++j) acc[i][j] = MFMA16(af[i], bfr[j], acc[i][j]);
    }
    __syncthreads();
  }

#pragma unroll
  for (int mi = 0; mi < 4; ++mi) {
    const int row = m0 + wm + mi * 16 + quad * 4;
#pragma unroll
    for (int ni = 0; ni < 2; ++ni) {
      const int col = n0 + wn + ni * 16 + lane15;
      const float bsum = bias[col];
#pragma unroll
      for (int r = 0; r < 4; ++r) {
        const size_t idx2 = (size_t)(row + r) * N + col;
        float v = acc[mi][ni][r] + bsum;
        if (GELU) v = gelu_f(v);
        if (RESID) v += resid[idx2];
        if (OUTBF16) outB[idx2] = (__bf16)v;
        else outF[idx2] = v;
      }
    }
  }
}

// ---------------- GEMM 128x128, distance-2 prefetch (Wout) -----------------
// For HBM-latency-bound A (64MB hb): A triple-buffered (staged 2 K-steps
// ahead), B double-buffered (1 ahead, L2-resident). Counted vmcnt(4) per
// step leaves only A(t+2) in flight: drains A(t+1) (age ~1.5 iter >= HBM
// latency) and B(t+1) (age ~1 compute span >= L2 latency). Never vmcnt(0)
// in steady state (T4). LDS 80KB -> 2 blocks/CU.
template <bool GELU, bool RESID, bool OUTBF16>
__global__ __launch_bounds__(256, 2) void gemm_dp_kernel(
    const __bf16* __restrict__ A, const __bf16* __restrict__ BT,
    const float* __restrict__ bias, const float* __restrict__ resid,
    float* __restrict__ outF, __bf16* __restrict__ outB, int M, int N, int K) {
  __shared__ __bf16 As[3][128 * 64];
  __shared__ __bf16 Bs[2][128 * 64];
  const int tid = threadIdx.x;
  const int wave = tid >> 6, lane = tid & 63;
  const int lane15 = lane & 15, quad = lane >> 4;
  const int r7 = lane15 & 7;

  int bm, bn;
  swizzle_mn(gridDim.x, gridDim.y, &bm, &bn);
  const int m0 = bm * 128, n0 = bn * 128;
  const int wm = (wave >> 1) * 64, wn = (wave & 1) * 64;

  const int srow = lane >> 3;
  const int gc8 = (lane & 7) ^ srow;
  const int NT = K >> 6;

  auto stageA = [&](int t, int buf) {
#pragma unroll
    for (int i = 0; i < 4; ++i) {
      const int row = wave * 32 + i * 8;
      gload16(A + (size_t)(m0 + row + srow) * K + t * 64 + gc8 * 8,
              &As[buf][row * 64]);
    }
  };
  auto stageB = [&](int t, int buf) {
#pragma unroll
    for (int i = 0; i < 4; ++i) {
      const int row = wave * 32 + i * 8;
      gload16(BT + (size_t)(n0 + row + srow) * K + t * 64 + gc8 * 8,
              &Bs[buf][row * 64]);
    }
  };

  floatx4 acc[4][4] = {};

  // prologue: B(0), A(0), A(1); vmcnt(4) drains B0,A0 and leaves A1 in flight
  stageB(0, 0);
  stageA(0, 0);
  if (NT > 1) stageA(1, 1);
  waitvm4();
  bar();

  int acur = 0;  // t % 3
  for (int t = 0; t < NT; ++t) {
    const int bcur = t & 1;
    // issue order matters for the counted wait: B(t+1) first, then A(t+2)
    if (t + 1 < NT) stageB(t + 1, bcur ^ 1);
    if (t + 2 < NT) stageA(t + 2, (acur + 2 >= 3) ? acur - 1 : acur + 2);
#pragma unroll
    for (int kk8 = 0; kk8 < 8; kk8 += 4) {
      bf16x8 af[4], bfr[4];
#pragma unroll
      for (int i = 0; i < 4; ++i) {
        af[i] = *(const bf16x8*)
            &As[acur][(wm + i * 16 + lane15) * 64 + (((kk8 + quad) ^ r7) << 3)];
        bfr[i] = *(const bf16x8*)
            &Bs[bcur][(wn + i * 16 + lane15) * 64 + (((kk8 + quad) ^ r7) << 3)];
      }
#pragma unroll
      for (int i = 0; i < 4; ++i)
#pragma unroll
        for (int j = 0; j < 4; ++j) acc[i][j] = MFMA16(af[i], bfr[j], acc[i][j]);
    }
    if (t + 1 < NT) {
      if (t + 2 < NT) waitvm4();  // leave only A(t+2)'s 4 loads in flight
      else waitvm0();             // tail: everything needed next step
      bar();
    }
    acur = (acur + 1 >= 3) ? 0 : acur + 1;
  }

#pragma unroll
  for (int mi = 0; mi < 4; ++mi) {
    const int row = m0 + wm + mi * 16 + quad * 4;
#pragma unroll
    for (int ni = 0; ni < 4; ++ni) {
      const int col = n0 + wn + ni * 16 + lane15;
      const float bsum = bias[col];
#pragma unroll
      for (int r = 0; r < 4; ++r) {
        const size_t idx2 = (size_t)(row + r) * N + col;
        float v = acc[mi][ni][r] + bsum;
        if (GELU) v = gelu_f(v);
        if (RESID) v += resid[idx2];
        if (OUTBF16) outB[idx2] = (__bf16)v;
        else outF[idx2] = v;
      }
    }
  }
}

// ------------------------------ flash attention ----------------------------
// S^T variant: QK computed as S^T = K*Q^T (A=K, B=Q) so lane holds q=lane15,
// kv=quad*4+r -> P values contiguous in kv -> one b64 Pt write per 16-tile.
// Pt is [q][kv] (A-layout for PV). Vt transpose uses kv-paired b32 writes.
#define PT_S 72
#define VT_S 72
__global__ __launch_bounds__(256, 4) void attn_kernel(
    const __bf16* __restrict__ qkv, __bf16* __restrict__ y) {
  const int linear = blockIdx.x;            // 0..1023
  const int xcd = linear & 7, idx = linear >> 3;
  const int pair = idx & 15;
  const int bh = xcd * 8 + (idx >> 4);      // 8 bh per XCD
  const int b = bh >> 4, h = bh & 15;

  const int tid = threadIdx.x, wave = tid >> 6, lane = tid & 63;
  const int lane15 = lane & 15, quad = lane >> 4;
  __shared__ __bf16 K0[2][64 * 32];     // [buf][kv][d 0..31]
  __shared__ __bf16 K1[2][64 * 32];     // [buf][kv][d 32..63]
  __shared__ __bf16 Vt[64 * VT_S];      // [d][kv], padded
  __shared__ __bf16 Pt[4][16 * PT_S];   // per-wave [q][kv], padded

  const int krow_loc = lane >> 2;            // 0..15
  const int kdc = (lane & 3) * 8;            // 0,8,16,24
  const int v_kvp = tid & 31;                // kv pair index 0..31
  const int v_dgrp = tid >> 5;               // 0..7 -> d group of 8
  const float QSCALE = 0.125f * 1.44269504088896f;

  const int qt_of[2] = {pair, 31 - pair};

  bf16x8 onesf;
#pragma unroll
  for (int j = 0; j < 8; ++j) onesf[j] = (__bf16)1.0f;

  bf16x8 vr0, vr1;   // prefetched V rows (kv even, kv odd) for d-group
  int g = 0;

  {
    const size_t gk =
        (size_t)(b * T_ + wave * 16 + krow_loc) * QKV_N + C_ + h * 64 + kdc;
    gload16(qkv + gk, &K0[0][wave * 16 * 32]);
    gload16(qkv + gk + 32, &K1[0][wave * 16 * 32]);
    const __bf16* vsrc = qkv + (size_t)(b * T_ + 2 * v_kvp) * QKV_N +
                         2 * C_ + h * 64 + v_dgrp * 8;
    vr0 = *(const bf16x8*)vsrc;
    vr1 = *(const bf16x8*)(vsrc + QKV_N);
  }

#pragma unroll
  for (int seg = 0; seg < 2; ++seg) {
    const int qt = qt_of[seg];
    const int qrow0 = qt * 64 + wave * 16;
    const int tq = qrow0 + lane15;          // this lane's q row (S^T layout)

    bf16x8 qf0, qf1;
    {
      const size_t base =
          (size_t)(b * T_ + qrow0 + lane15) * QKV_N + h * 64 + quad * 8;
      const bf16x8 r0 = *(const bf16x8*)(qkv + base);
      const bf16x8 r1 = *(const bf16x8*)(qkv + base + 32);
#pragma unroll
      for (int j = 0; j < 8; ++j) {
        qf0[j] = (__bf16)((float)r0[j] * QSCALE);
        qf1[j] = (__bf16)((float)r1[j] * QSCALE);
      }
    }

    floatx4 o[4] = {};
    floatx4 o4 = {0.f, 0.f, 0.f, 0.f};   // row sums via ones-fragment MFMA

    const int ntiles = qt + 1;
    for (int kvt = 0; kvt < ntiles; ++kvt) {
      const int buf = g & 1;
      const int c0 = kvt * 64;
      const bool has_next = !(seg == 1 && kvt + 1 >= ntiles);
      const int nkvt = (kvt + 1 >= ntiles) ? 0 : kvt + 1;
      const int nc0 = nkvt * 64;
      const int nbuf = (g + 1) & 1;

      // (1) WAR guard for Vt overwrite + publish point for K[nbuf] readers.
      bar();

      // ---- issue NEXT tile's K loads early (hide under commit+QK) ----
      if (has_next) {
        const size_t gk = (size_t)(b * T_ + nc0 + wave * 16 + krow_loc) * QKV_N +
                          C_ + h * 64 + kdc;
        gload16(qkv + gk, &K0[nbuf][wave * 16 * 32]);
        gload16(qkv + gk + 32, &K1[nbuf][wave * 16 * 32]);
      }

      // ---- commit prefetched V rows, kv-paired b32 writes ----
#pragma unroll
      for (int j = 0; j < 8; ++j) {
        union { __bf16 hh[2]; uint32_t u; } pk;
        pk.hh[0] = vr0[j];
        pk.hh[1] = vr1[j];
        *(uint32_t*)&Vt[(v_dgrp * 8 + j) * VT_S + 2 * v_kvp] = pk.u;
      }
      // (2) publish Vt writes: lgkm-only fence + barrier (no vmcnt drain)
      lds_fence();
      bar();

      // ---- issue NEXT tile's register V loads ----
      if (has_next) {
        const __bf16* vsrc = qkv + (size_t)(b * T_ + nc0 + 2 * v_kvp) * QKV_N +
                             2 * C_ + h * 64 + v_dgrp * 8;
        vr0 = *(const bf16x8*)vsrc;
        vr1 = *(const bf16x8*)(vsrc + QKV_N);
      }

      // ---- S^T = K Q^T : lane holds q=lane15, kv rows quad*4+r ----
#pragma unroll
      for (int nt = 0; nt < 4; ++nt) {
        const bf16x8 kf0 =
            *(const bf16x8*)&K0[buf][(nt * 16 + lane15) * 32 + quad * 8];
        const bf16x8 kf1 =
            *(const bf16x8*)&K1[buf][(nt * 16 + lane15) * 32 + quad * 8];
        floatx4 s = {0.f, 0.f, 0.f, 0.f};
        s = MFMA16(kf0, qf0, s);
        s = MFMA16(kf1, qf1, s);
        const int tk0 = c0 + nt * 16 + quad * 4;  // kv of reg r
        bf16x4 pk4;
        if (kvt == qt) {
#pragma unroll
          for (int r = 0; r < 4; ++r) {
            const float sv = (tk0 + r <= tq) ? s[r] : -1e30f;
            pk4[r] = (__bf16)__builtin_amdgcn_exp2f(sv);
          }
        } else {
#pragma unroll
          for (int r = 0; r < 4; ++r)
            pk4[r] = (__bf16)__builtin_amdgcn_exp2f(s[r]);
        }
        // packed b64 write: Pt[q=lane15][kv = nt*16 + quad*4 .. +3]
        *(bf16x4*)&Pt[wave][lane15 * PT_S + nt * 16 + quad * 4] = pk4;
      }
      lds_fence();

      // ---- PV (+ ones-column row sums) ----
#pragma unroll
      for (int half = 0; half < 2; ++half) {
        const bf16x8 pf =
            *(const bf16x8*)&Pt[wave][lane15 * PT_S + half * 32 + quad * 8];
#pragma unroll
        for (int dt = 0; dt < 4; ++dt) {
          const bf16x8 vf =
              *(const bf16x8*)&Vt[(dt * 16 + lane15) * VT_S + half * 32 + quad * 8];
          o[dt] = MFMA16(pf, vf, o[dt]);
        }
        o4 = MFMA16(pf, onesf, o4);
      }
      ++g;
    }

#pragma unroll
    for (int r = 0; r < 4; ++r) {
      const int tqo = qrow0 + quad * 4 + r;
      const float inv = 1.0f / o4[r];
#pragma unroll
      for (int dt = 0; dt < 4; ++dt)
        y[(size_t)(b * T_ + tqo) * C_ + h * 64 + dt * 16 + lane15] =
            (__bf16)(o[dt][r] * inv);
    }
  }
}

// --------------------------------- launcher --------------------------------
extern "C" void kernel_launch(void* const* d_in, const int* in_sizes, int n_in,
                              void* d_out, int out_size, void* d_ws,
                              size_t ws_size, hipStream_t stream) {
  const float* x     = (const float*)d_in[0];
  const float* ln1_w = (const float*)d_in[1];
  const float* ln1_b = (const float*)d_in[2];
  const float* w_qkv = (const float*)d_in[3];
  const float* b_qkv = (const float*)d_in[4];
  const float* w_o   = (const float*)d_in[5];
  const float* b_o   = (const float*)d_in[6];
  const float* ln2_w = (const float*)d_in[7];
  const float* ln2_b = (const float*)d_in[8];
  const float* w_fc  = (const float*)d_in[9];
  const float* b_fc  = (const float*)d_in[10];
  const float* w_out = (const float*)d_in[11];
  const float* b_out = (const float*)d_in[12];

  char* ws = (char*)d_ws;
  __bf16* wqkvT = (__bf16*)(ws + 0);                  // [3072][1024]  6 MB
  __bf16* woT   = (__bf16*)(ws + 6291456);            // [1024][1024]  2 MB
  __bf16* wfcT  = (__bf16*)(ws + 8388608);            // [4096][1024]  8 MB
  __bf16* woutT = (__bf16*)(ws + 16777216);           // [1024][4096]  8 MB
  __bf16* xn    = (__bf16*)(ws + 25165824);           // [8192][1024] 16 MB
  __bf16* qkv   = (__bf16*)(ws + 41943040);           // [8192][3072] 48 MB
  __bf16* yb    = (__bf16*)(ws + 92274688);           // [8192][1024] 16 MB
  float*  x1    = (float*)(ws + 109051904);           // [8192][1024] 32 MB
  __bf16* hb    = (__bf16*)(ws + 142606336);          // [8192][4096] 64 MB

  head_kernel<<<20480, 256, 0, stream>>>(w_qkv, w_o, w_fc, w_out,
                                         wqkvT, woT, wfcT, woutT,
                                         x, ln1_w, ln1_b, xn);

  gemm_kernel<false, false, true><<<dim3(QKV_N / 128, M_ / 128), 256, 0, stream>>>(
      xn, wqkvT, b_qkv, nullptr, nullptr, qkv, M_, QKV_N, C_);
  attn_kernel<<<1024, 256, 0, stream>>>(qkv, yb);
  gemm_n64_kernel<false, true, false><<<dim3(C_ / 64, M_ / 128), 256, 0, stream>>>(
      yb, woT, b_o, x, x1, nullptr, M_, C_, C_);
  ln_kernel<<<M_, 256, 0, stream>>>(x1, ln2_w, ln2_b, xn);
  gemm_kernel<true, false, true><<<dim3(FF_ / 128, M_ / 128), 256, 0, stream>>>(
      xn, wfcT, b_fc, nullptr, nullptr, hb, M_, FF_, C_);
  gemm_dp_kernel<false, true, false><<<dim3(C_ / 128, M_ / 128), 256, 0, stream>>>(
      hb, woutT, b_out, x1, (float*)d_out, nullptr, M_, C_, FF_);
}

// Round 13
// 425.627 us; speedup vs baseline: 1.0382x; 1.0382x over previous
//
#include <hip/hip_runtime.h>
#include <hip/hip_bf16.h>
#include <cstdint>

// ---------------------------------------------------------------------------
// Transformer block forward (B=4,T=2048,H=16,D=64,C=1024,FF=4096), bf16 MFMA.
// Round 20: locked 433 µs build + bf16 residual stream. x1 (= x + attn@Wo)
// stored bf16 instead of fp32: WO writes 16 MB (was 32), LN2 reads 16 (was
// 32), Wout's resid read 16 (was 32) — minus ~48 MB HBM. Numerics: bf16
// round-off ~0.004-0.01 abs, margin 0.03125 -> 0.116 ample. GEMM structure
// closed (rounds 5-12: occupancy/BK/prefetch-depth/wait-discipline all
// neutral-or-worse vs the m97 128x128 structure).
// ---------------------------------------------------------------------------

#define B_ 4
#define T_ 2048
#define H_ 16
#define D_ 64
#define C_ 1024
#define FF_ 4096
#define M_ (B_ * T_)          // 8192 rows
#define QKV_N (3 * C_)        // 3072

typedef __bf16 bf16x8 __attribute__((ext_vector_type(8)));
typedef __bf16 bf16x4 __attribute__((ext_vector_type(4)));
typedef float floatx4 __attribute__((ext_vector_type(4)));

#define MFMA16(a, b, c) __builtin_amdgcn_mfma_f32_16x16x32_bf16(a, b, c, 0, 0, 0)

__device__ __forceinline__ void gload16(const void* g, void* l) {
  __builtin_amdgcn_global_load_lds(
      (const __attribute__((address_space(1))) void*)g,
      (__attribute__((address_space(3))) void*)l, 16, 0, 0);
}

__device__ __forceinline__ void lds_fence() {
  asm volatile("s_waitcnt lgkmcnt(0)" ::: "memory");
}

// raw barrier: does NOT drain vmcnt (unlike __syncthreads)
__device__ __forceinline__ void bar() {
  asm volatile("" ::: "memory");
  __builtin_amdgcn_s_barrier();
  asm volatile("" ::: "memory");
}

// tanh-approx GELU via exp2: gelu(x) = x - x/(exp2(k1*x + ck*x^3) + 1)
__device__ __forceinline__ float gelu_f(float x) {
  const float k1 = 2.3021178518f;     // 2*log2(e)*0.7978845608
  const float ck = 0.1029410426f;     // k1*0.044715
  const float y = x * __builtin_fmaf(x * x, ck, k1);
  const float t = __builtin_amdgcn_exp2f(y);
  return x - x * __builtin_amdgcn_rcpf(t + 1.0f);
}

// ---------------- head: weight convert+transpose (x4) + LN1 ----------------
__global__ __launch_bounds__(256) void head_kernel(
    const float* __restrict__ wqkv, const float* __restrict__ wo,
    const float* __restrict__ wfc, const float* __restrict__ wout,
    __bf16* __restrict__ dqkv, __bf16* __restrict__ dwo,
    __bf16* __restrict__ dfc, __bf16* __restrict__ dwout,
    const float* __restrict__ x, const float* __restrict__ lnw,
    const float* __restrict__ lnb, __bf16* __restrict__ xn) {
  __shared__ float tile[32][33];
  __shared__ float red[4];
  int bx = blockIdx.x;
  const int tid = threadIdx.x;

  if (bx >= 12288) {
    const int row = bx - 12288;
    const float4 v = ((const float4*)(x + (size_t)row * C_))[tid];
    float s = v.x + v.y + v.z + v.w;
#pragma unroll
    for (int off = 1; off < 64; off <<= 1) s += __shfl_xor(s, off, 64);
    if ((tid & 63) == 0) red[tid >> 6] = s;
    __syncthreads();
    const float mean = (red[0] + red[1] + red[2] + red[3]) * (1.0f / C_);
    __syncthreads();
    const float dx = v.x - mean, dy = v.y - mean, dz = v.z - mean,
                dw = v.w - mean;
    float s2 = dx * dx + dy * dy + dz * dz + dw * dw;
#pragma unroll
    for (int off = 1; off < 64; off <<= 1) s2 += __shfl_xor(s2, off, 64);
    if ((tid & 63) == 0) red[tid >> 6] = s2;
    __syncthreads();
    const float var = (red[0] + red[1] + red[2] + red[3]) * (1.0f / C_);
    const float rstd = rsqrtf(var + 1e-5f);
    const float4 wv = ((const float4*)lnw)[tid];
    const float4 bv = ((const float4*)lnb)[tid];
    bf16x4 o;
    o[0] = (__bf16)(dx * rstd * wv.x + bv.x);
    o[1] = (__bf16)(dy * rstd * wv.y + bv.y);
    o[2] = (__bf16)(dz * rstd * wv.z + bv.z);
    o[3] = (__bf16)(dw * rstd * wv.w + bv.w);
    *(bf16x4*)(xn + (size_t)row * C_ + tid * 4) = o;
    return;
  }

  const float* src;
  __bf16* dst;
  int K, N;
  if (bx < 3072)      { src = wqkv; dst = dqkv; K = 1024; N = 3072; }
  else if (bx < 4096) { bx -= 3072; src = wo;   dst = dwo;   K = 1024; N = 1024; }
  else if (bx < 8192) { bx -= 4096; src = wfc;  dst = dfc;   K = 1024; N = 4096; }
  else                { bx -= 8192; src = wout; dst = dwout; K = 4096; N = 1024; }
  const int tn = N >> 5;
  const int n0 = (bx % tn) * 32, k0 = (bx / tn) * 32;
  const int tx = tid & 31, ty = tid >> 5;  // 32 x 8
#pragma unroll
  for (int i = 0; i < 4; ++i)
    tile[ty + i * 8][tx] = src[(size_t)(k0 + ty + i * 8) * N + n0 + tx];
  __syncthreads();
#pragma unroll
  for (int i = 0; i < 4; ++i)
    dst[(size_t)(n0 + ty + i * 8) * K + k0 + tx] = (__bf16)tile[tx][ty + i * 8];
}

// --------------------- layernorm (LN2, bf16 input) -------------------------
__global__ __launch_bounds__(256) void ln_bf16_kernel(
    const __bf16* __restrict__ x, const float* __restrict__ w,
    const float* __restrict__ b, __bf16* __restrict__ out) {
  __shared__ float red[4];
  const int row = blockIdx.x, tid = threadIdx.x;
  const bf16x4 vv = *(const bf16x4*)(x + (size_t)row * C_ + tid * 4);
  const float v0 = (float)vv[0], v1 = (float)vv[1],
              v2 = (float)vv[2], v3 = (float)vv[3];
  float s = v0 + v1 + v2 + v3;
#pragma unroll
  for (int off = 1; off < 64; off <<= 1) s += __shfl_xor(s, off, 64);
  if ((tid & 63) == 0) red[tid >> 6] = s;
  __syncthreads();
  const float mean = (red[0] + red[1] + red[2] + red[3]) * (1.0f / C_);
  __syncthreads();
  const float dx = v0 - mean, dy = v1 - mean, dz = v2 - mean, dw = v3 - mean;
  float s2 = dx * dx + dy * dy + dz * dz + dw * dw;
#pragma unroll
  for (int off = 1; off < 64; off <<= 1) s2 += __shfl_xor(s2, off, 64);
  if ((tid & 63) == 0) red[tid >> 6] = s2;
  __syncthreads();
  const float var = (red[0] + red[1] + red[2] + red[3]) * (1.0f / C_);
  const float rstd = rsqrtf(var + 1e-5f);
  const float4 wv = ((const float4*)w)[tid];
  const float4 bv = ((const float4*)b)[tid];
  bf16x4 o;
  o[0] = (__bf16)(dx * rstd * wv.x + bv.x);
  o[1] = (__bf16)(dy * rstd * wv.y + bv.y);
  o[2] = (__bf16)(dz * rstd * wv.z + bv.z);
  o[3] = (__bf16)(dw * rstd * wv.w + bv.w);
  *(bf16x4*)(out + (size_t)row * C_ + tid * 4) = o;
}

// --------------------- swizzle: XCD band + 8x8 L2 groups -------------------
__device__ __forceinline__ void swizzle_mn(int gx, int gy, int* bm, int* bn) {
  const int linear = blockIdx.y * gx + blockIdx.x;
  const int xcd = linear & 7, idx = linear >> 3;
  const int band = gy >> 3;
  const int per_grp = band * 8;
  const int g = idx / per_grp, rem = idx % per_grp;
  *bm = xcd * band + rem % band;
  *bn = g * 8 + rem / band;
}

// ------------------------------- GEMM 128x128 ------------------------------
// RESID: fp32 residual; RESIDB: bf16 residual (x1b path).
template <bool GELU, bool RESID, bool RESIDB, bool OUTBF16>
__global__ __launch_bounds__(256, 2) void gemm_kernel(
    const __bf16* __restrict__ A, const __bf16* __restrict__ BT,
    const float* __restrict__ bias, const float* __restrict__ resid,
    const __bf16* __restrict__ residb,
    float* __restrict__ outF, __bf16* __restrict__ outB, int M, int N, int K) {
  __shared__ __bf16 As[128 * 64];
  __shared__ __bf16 Bs[128 * 64];
  const int tid = threadIdx.x;
  const int wave = tid >> 6, lane = tid & 63;
  const int lane15 = lane & 15, quad = lane >> 4;
  const int r7 = lane15 & 7;

  int bm, bn;
  swizzle_mn(gridDim.x, gridDim.y, &bm, &bn);
  const int m0 = bm * 128, n0 = bn * 128;
  const int wm = (wave >> 1) * 64, wn = (wave & 1) * 64;

  const int srow = lane >> 3;                 // 0..7 within 8-row chunk
  const int gc8 = (lane & 7) ^ srow;          // xor-swizzled column group

  floatx4 acc[4][4] = {};

  for (int k0 = 0; k0 < K; k0 += 64) {
#pragma unroll
    for (int t = 0; t < 4; ++t) {
      const int row = wave * 32 + t * 8;
      gload16(A + (size_t)(m0 + row + srow) * K + k0 + gc8 * 8, &As[row * 64]);
      gload16(BT + (size_t)(n0 + row + srow) * K + k0 + gc8 * 8, &Bs[row * 64]);
    }
    __syncthreads();
#pragma unroll
    for (int kk8 = 0; kk8 < 8; kk8 += 4) {
      bf16x8 af[4], bfr[4];
#pragma unroll
      for (int i = 0; i < 4; ++i) {
        af[i] = *(const bf16x8*)
            &As[(wm + i * 16 + lane15) * 64 + (((kk8 + quad) ^ r7) << 3)];
        bfr[i] = *(const bf16x8*)
            &Bs[(wn + i * 16 + lane15) * 64 + (((kk8 + quad) ^ r7) << 3)];
      }
#pragma unroll
      for (int i = 0; i < 4; ++i)
#pragma unroll
        for (int j = 0; j < 4; ++j) acc[i][j] = MFMA16(af[i], bfr[j], acc[i][j]);
    }
    __syncthreads();
  }

#pragma unroll
  for (int mi = 0; mi < 4; ++mi) {
    const int row = m0 + wm + mi * 16 + quad * 4;
#pragma unroll
    for (int ni = 0; ni < 4; ++ni) {
      const int col = n0 + wn + ni * 16 + lane15;
      const float bsum = bias[col];
#pragma unroll
      for (int r = 0; r < 4; ++r) {
        const size_t idx2 = (size_t)(row + r) * N + col;
        float v = acc[mi][ni][r] + bsum;
        if (GELU) v = gelu_f(v);
        if (RESID) v += resid[idx2];
        if (RESIDB) v += (float)residb[idx2];
        if (OUTBF16) outB[idx2] = (__bf16)v;
        else outF[idx2] = v;
      }
    }
  }
}

// ------------------------------- GEMM 128x64 -------------------------------
template <bool GELU, bool RESID, bool OUTBF16>
__global__ __launch_bounds__(256, 4) void gemm_n64_kernel(
    const __bf16* __restrict__ A, const __bf16* __restrict__ BT,
    const float* __restrict__ bias, const float* __restrict__ resid,
    float* __restrict__ outF, __bf16* __restrict__ outB, int M, int N, int K) {
  __shared__ __bf16 As[128 * 64];
  __shared__ __bf16 Bs[64 * 64];
  const int tid = threadIdx.x;
  const int wave = tid >> 6, lane = tid & 63;
  const int lane15 = lane & 15, quad = lane >> 4;
  const int r7 = lane15 & 7;

  int bm, bn;
  swizzle_mn(gridDim.x, gridDim.y, &bm, &bn);
  const int m0 = bm * 128, n0 = bn * 64;
  const int wm = (wave >> 1) * 64, wn = (wave & 1) * 32;

  const int srow = lane >> 3;
  const int gc8 = (lane & 7) ^ srow;

  floatx4 acc[4][2] = {};

  for (int k0 = 0; k0 < K; k0 += 64) {
#pragma unroll
    for (int t = 0; t < 4; ++t) {
      const int row = wave * 32 + t * 8;
      gload16(A + (size_t)(m0 + row + srow) * K + k0 + gc8 * 8, &As[row * 64]);
    }
#pragma unroll
    for (int t = 0; t < 2; ++t) {
      const int row = wave * 16 + t * 8;
      gload16(BT + (size_t)(n0 + row + srow) * K + k0 + gc8 * 8, &Bs[row * 64]);
    }
    __syncthreads();
#pragma unroll
    for (int kk8 = 0; kk8 < 8; kk8 += 4) {
      bf16x8 af[4], bfr[2];
#pragma unroll
      for (int i = 0; i < 4; ++i)
        af[i] = *(const bf16x8*)
            &As[(wm + i * 16 + lane15) * 64 + (((kk8 + quad) ^ r7) << 3)];
#pragma unroll
      for (int j = 0; j < 2; ++j)
        bfr[j] = *(const bf16x8*)
            &Bs[(wn + j * 16 + lane15) * 64 + (((kk8 + quad) ^ r7) << 3)];
#pragma unroll
      for (int i = 0; i < 4; ++i)
#pragma unroll
        for (int j = 0; j < 2; ++j) acc[i][j] = MFMA16(af[i], bfr[j], acc[i][j]);
    }
    __syncthreads();
  }

#pragma unroll
  for (int mi = 0; mi < 4; ++mi) {
    const int row = m0 + wm + mi * 16 + quad * 4;
#pragma unroll
    for (int ni = 0; ni < 2; ++ni) {
      const int col = n0 + wn + ni * 16 + lane15;
      const float bsum = bias[col];
#pragma unroll
      for (int r = 0; r < 4; ++r) {
        const size_t idx2 = (size_t)(row + r) * N + col;
        float v = acc[mi][ni][r] + bsum;
        if (GELU) v = gelu_f(v);
        if (RESID) v += resid[idx2];
        if (OUTBF16) outB[idx2] = (__bf16)v;
        else outF[idx2] = v;
      }
    }
  }
}

// ------------------------------ flash attention ----------------------------
// S^T variant: QK computed as S^T = K*Q^T (A=K, B=Q) so lane holds q=lane15,
// kv=quad*4+r -> P values contiguous in kv -> one b64 Pt write per 16-tile.
// Pt is [q][kv] (A-layout for PV). Vt transpose uses kv-paired b32 writes.
//
// kv-loop barriers use raw s_barrier (no vmcnt drain). Next-tile K
// global_load_lds issue immediately after the tile-start barrier: race-free
// (all K[nbuf] readers finished before that barrier); vr loads issue after
// the commit -> FIFO vmcnt transitively drains K stages before the publish.
#define PT_S 72
#define VT_S 72
__global__ __launch_bounds__(256, 4) void attn_kernel(
    const __bf16* __restrict__ qkv, __bf16* __restrict__ y) {
  const int linear = blockIdx.x;            // 0..1023
  const int xcd = linear & 7, idx = linear >> 3;
  const int pair = idx & 15;
  const int bh = xcd * 8 + (idx >> 4);      // 8 bh per XCD
  const int b = bh >> 4, h = bh & 15;

  const int tid = threadIdx.x, wave = tid >> 6, lane = tid & 63;
  const int lane15 = lane & 15, quad = lane >> 4;
  __shared__ __bf16 K0[2][64 * 32];     // [buf][kv][d 0..31]
  __shared__ __bf16 K1[2][64 * 32];     // [buf][kv][d 32..63]
  __shared__ __bf16 Vt[64 * VT_S];      // [d][kv], padded
  __shared__ __bf16 Pt[4][16 * PT_S];   // per-wave [q][kv], padded

  const int krow_loc = lane >> 2;            // 0..15
  const int kdc = (lane & 3) * 8;            // 0,8,16,24
  const int v_kvp = tid & 31;                // kv pair index 0..31
  const int v_dgrp = tid >> 5;               // 0..7 -> d group of 8
  const float QSCALE = 0.125f * 1.44269504088896f;

  const int qt_of[2] = {pair, 31 - pair};

  bf16x8 onesf;
#pragma unroll
  for (int j = 0; j < 8; ++j) onesf[j] = (__bf16)1.0f;

  bf16x8 vr0, vr1;   // prefetched V rows (kv even, kv odd) for d-group
  int g = 0;

  {
    const size_t gk =
        (size_t)(b * T_ + wave * 16 + krow_loc) * QKV_N + C_ + h * 64 + kdc;
    gload16(qkv + gk, &K0[0][wave * 16 * 32]);
    gload16(qkv + gk + 32, &K1[0][wave * 16 * 32]);
    const __bf16* vsrc = qkv + (size_t)(b * T_ + 2 * v_kvp) * QKV_N +
                         2 * C_ + h * 64 + v_dgrp * 8;
    vr0 = *(const bf16x8*)vsrc;
    vr1 = *(const bf16x8*)(vsrc + QKV_N);
  }

#pragma unroll
  for (int seg = 0; seg < 2; ++seg) {
    const int qt = qt_of[seg];
    const int qrow0 = qt * 64 + wave * 16;
    const int tq = qrow0 + lane15;          // this lane's q row (S^T layout)

    bf16x8 qf0, qf1;
    {
      const size_t base =
          (size_t)(b * T_ + qrow0 + lane15) * QKV_N + h * 64 + quad * 8;
      const bf16x8 r0 = *(const bf16x8*)(qkv + base);
      const bf16x8 r1 = *(const bf16x8*)(qkv + base + 32);
#pragma unroll
      for (int j = 0; j < 8; ++j) {
        qf0[j] = (__bf16)((float)r0[j] * QSCALE);
        qf1[j] = (__bf16)((float)r1[j] * QSCALE);
      }
    }

    floatx4 o[4] = {};
    floatx4 o4 = {0.f, 0.f, 0.f, 0.f};   // row sums via ones-fragment MFMA

    const int ntiles = qt + 1;
    for (int kvt = 0; kvt < ntiles; ++kvt) {
      const int buf = g & 1;
      const int c0 = kvt * 64;
      const bool has_next = !(seg == 1 && kvt + 1 >= ntiles);
      const int nkvt = (kvt + 1 >= ntiles) ? 0 : kvt + 1;
      const int nc0 = nkvt * 64;
      const int nbuf = (g + 1) & 1;

      // (1) WAR guard for Vt overwrite + publish point for K[nbuf] readers.
      bar();

      // ---- issue NEXT tile's K loads early (hide under commit+QK) ----
      if (has_next) {
        const size_t gk = (size_t)(b * T_ + nc0 + wave * 16 + krow_loc) * QKV_N +
                          C_ + h * 64 + kdc;
        gload16(qkv + gk, &K0[nbuf][wave * 16 * 32]);
        gload16(qkv + gk + 32, &K1[nbuf][wave * 16 * 32]);
      }

      // ---- commit prefetched V rows, kv-paired b32 writes ----
#pragma unroll
      for (int j = 0; j < 8; ++j) {
        union { __bf16 hh[2]; uint32_t u; } pk;
        pk.hh[0] = vr0[j];
        pk.hh[1] = vr1[j];
        *(uint32_t*)&Vt[(v_dgrp * 8 + j) * VT_S + 2 * v_kvp] = pk.u;
      }
      // (2) publish Vt writes: lgkm-only fence + barrier (no vmcnt drain)
      lds_fence();
      bar();

      // ---- issue NEXT tile's register V loads ----
      if (has_next) {
        const __bf16* vsrc = qkv + (size_t)(b * T_ + nc0 + 2 * v_kvp) * QKV_N +
                             2 * C_ + h * 64 + v_dgrp * 8;
        vr0 = *(const bf16x8*)vsrc;
        vr1 = *(const bf16x8*)(vsrc + QKV_N);
      }

      // ---- S^T = K Q^T : lane holds q=lane15, kv rows quad*4+r ----
#pragma unroll
      for (int nt = 0; nt < 4; ++nt) {
        const bf16x8 kf0 =
            *(const bf16x8*)&K0[buf][(nt * 16 + lane15) * 32 + quad * 8];
        const bf16x8 kf1 =
            *(const bf16x8*)&K1[buf][(nt * 16 + lane15) * 32 + quad * 8];
        floatx4 s = {0.f, 0.f, 0.f, 0.f};
        s = MFMA16(kf0, qf0, s);
        s = MFMA16(kf1, qf1, s);
        const int tk0 = c0 + nt * 16 + quad * 4;  // kv of reg r
        bf16x4 pk4;
        if (kvt == qt) {
#pragma unroll
          for (int r = 0; r < 4; ++r) {
            const float sv = (tk0 + r <= tq) ? s[r] : -1e30f;
            pk4[r] = (__bf16)__builtin_amdgcn_exp2f(sv);
          }
        } else {
#pragma unroll
          for (int r = 0; r < 4; ++r)
            pk4[r] = (__bf16)__builtin_amdgcn_exp2f(s[r]);
        }
        // packed b64 write: Pt[q=lane15][kv = nt*16 + quad*4 .. +3]
        *(bf16x4*)&Pt[wave][lane15 * PT_S + nt * 16 + quad * 4] = pk4;
      }
      lds_fence();

      // ---- PV (+ ones-column row sums) ----
#pragma unroll
      for (int half = 0; half < 2; ++half) {
        const bf16x8 pf =
            *(const bf16x8*)&Pt[wave][lane15 * PT_S + half * 32 + quad * 8];
#pragma unroll
        for (int dt = 0; dt < 4; ++dt) {
          const bf16x8 vf =
              *(const bf16x8*)&Vt[(dt * 16 + lane15) * VT_S + half * 32 + quad * 8];
          o[dt] = MFMA16(pf, vf, o[dt]);
        }
        o4 = MFMA16(pf, onesf, o4);
      }
      ++g;
    }

#pragma unroll
    for (int r = 0; r < 4; ++r) {
      const int tqo = qrow0 + quad * 4 + r;
      const float inv = 1.0f / o4[r];
#pragma unroll
      for (int dt = 0; dt < 4; ++dt)
        y[(size_t)(b * T_ + tqo) * C_ + h * 64 + dt * 16 + lane15] =
            (__bf16)(o[dt][r] * inv);
    }
  }
}

// --------------------------------- launcher --------------------------------
extern "C" void kernel_launch(void* const* d_in, const int* in_sizes, int n_in,
                              void* d_out, int out_size, void* d_ws,
                              size_t ws_size, hipStream_t stream) {
  const float* x     = (const float*)d_in[0];
  const float* ln1_w = (const float*)d_in[1];
  const float* ln1_b = (const float*)d_in[2];
  const float* w_qkv = (const float*)d_in[3];
  const float* b_qkv = (const float*)d_in[4];
  const float* w_o   = (const float*)d_in[5];
  const float* b_o   = (const float*)d_in[6];
  const float* ln2_w = (const float*)d_in[7];
  const float* ln2_b = (const float*)d_in[8];
  const float* w_fc  = (const float*)d_in[9];
  const float* b_fc  = (const float*)d_in[10];
  const float* w_out = (const float*)d_in[11];
  const float* b_out = (const float*)d_in[12];

  char* ws = (char*)d_ws;
  __bf16* wqkvT = (__bf16*)(ws + 0);                  // [3072][1024]  6 MB
  __bf16* woT   = (__bf16*)(ws + 6291456);            // [1024][1024]  2 MB
  __bf16* wfcT  = (__bf16*)(ws + 8388608);            // [4096][1024]  8 MB
  __bf16* woutT = (__bf16*)(ws + 16777216);           // [1024][4096]  8 MB
  __bf16* xn    = (__bf16*)(ws + 25165824);           // [8192][1024] 16 MB
  __bf16* qkv   = (__bf16*)(ws + 41943040);           // [8192][3072] 48 MB
  __bf16* yb    = (__bf16*)(ws + 92274688);           // [8192][1024] 16 MB
  __bf16* x1b   = (__bf16*)(ws + 109051904);          // [8192][1024] 16 MB
  __bf16* hb    = (__bf16*)(ws + 142606336);          // [8192][4096] 64 MB

  head_kernel<<<20480, 256, 0, stream>>>(w_qkv, w_o, w_fc, w_out,
                                         wqkvT, woT, wfcT, woutT,
                                         x, ln1_w, ln1_b, xn);

  gemm_kernel<false, false, false, true><<<dim3(QKV_N / 128, M_ / 128), 256, 0, stream>>>(
      xn, wqkvT, b_qkv, nullptr, nullptr, nullptr, qkv, M_, QKV_N, C_);
  attn_kernel<<<1024, 256, 0, stream>>>(qkv, yb);
  gemm_n64_kernel<false, true, true><<<dim3(C_ / 64, M_ / 128), 256, 0, stream>>>(
      yb, woT, b_o, x, nullptr, x1b, M_, C_, C_);
  ln_bf16_kernel<<<M_, 256, 0, stream>>>(x1b, ln2_w, ln2_b, xn);
  gemm_kernel<true, false, false, true><<<dim3(FF_ / 128, M_ / 128), 256, 0, stream>>>(
      xn, wfcT, b_fc, nullptr, nullptr, nullptr, hb, M_, FF_, C_);
  gemm_kernel<false, false, true, false><<<dim3(C_ / 128, M_ / 128), 256, 0, stream>>>(
      hb, woutT, b_out, nullptr, x1b, (float*)d_out, nullptr, M_, C_, FF_);
}